// Round 7
// baseline (224.700 us; speedup 1.0000x reference)
//
#include <hip/hip_runtime.h>
#include <stdint.h>

// Problem constants (fixed by setup_inputs)
constexpr int B_SZ     = 128;
constexpr int IN_CAPS  = 1152;
constexpr int OUT_CAPS = 32;
constexpr int OUT_D    = 16;
constexpr int ITERS    = 3;

constexpr int THREADS  = 1024;              // 16 waves
constexpr int NW       = THREADS / 64;      // 16
constexpr int G        = 2;                 // batches per block
constexpr int TILE_R   = 128;               // i-rows per LDS tile
constexpr int NTILE    = IN_CAPS / TILE_R;  // 9

// bf16 weight tile, n-pair interleaved: row = 16 chunks x 16B = 256B.
// Chunk (t, mq) holds dwords k=0..3: (lo=w[2t, mq*4+k], hi=w[2t+1, mq*4+k]).
// Physical chunk = logical ^ (row & 7)  (XOR swizzle, both write & read side).
//
// R5/R6 lesson: SQ_LDS_BANK_CONFLICT was identical (9437184) under two
// different swizzles -> it's the data-limited floor (32 distinct 16B chunks
// per wave read = 4 LDS clocks), not fixable. So reduce the NUMBER of LDS
// instructions instead: bf16 halves reads (4 b128/thread/tile) and halves
// tile size (32KB -> 2x32KB double buffer = 68KB total, 2-blocks/CU eligible).
// R6 lesson: removing the double buffer serialized stage->compute; restore it.
__global__ __launch_bounds__(THREADS) void caps_route(
    const float* __restrict__ u,   // [B, IN_CAPS, IN_D=8]
    const float* __restrict__ w,   // [IN_CAPS, OUT_CAPS, 8, 16]
    float* __restrict__ out)       // [B, OUT_CAPS, OUT_D]
{
    __shared__ __align__(16) uint32_t tile[2][TILE_R * 64];  // 2 x 32 KB
    __shared__ float red_es[8 * NW];                         // [grp][q]
    __shared__ __align__(16) float red_m[8 * NW * 4];        // [grp][q][4]

    // Bijective XCD swizzle (2048 % 8 == 0): j-major ids -> each XCD's L2
    // holds 4 j-columns (2.3 MB < 4 MB).
    const int nwg = gridDim.x;               // 2048
    const int bid = blockIdx.x;
    const int wid = (bid & 7) * (nwg >> 3) + (bid >> 3);
    const int j   = wid >> 6;                // 0..31
    const int b0  = (wid & 63) * G;          // 0..126 step 2

    const int tid  = threadIdx.x;
    const int lane = tid & 63;
    const int wv   = tid >> 6;               // wave 0..15
    const int bl   = tid & 1;                // batch within pair
    const int mq   = (tid >> 1) & 3;         // m-quarter
    const int ir   = tid >> 3;               // i-row in tile, 0..127
    const int ir3  = ir & 7;
    const int b    = b0 + bl;

    // staging: thread owns (srow = tid>>3, logical chunks sc0 and sc0+8)
    const int srow = tid >> 3;
    const int sc0  = tid & 7;

    float uh[NTILE][4];                      // 36 VGPRs, literal indexing

    // load f32 source for logical chunk C2 of tile T (row srow)
    #define GLOADS(T, C2, RA, RB)                                             \
    do {                                                                      \
        const float* gb = w +                                                 \
            (((size_t)((T) * TILE_R + srow) * OUT_CAPS + j) << 7);            \
        const int t_ = (C2) >> 2, mqs = (C2) & 3;                             \
        RA = *reinterpret_cast<const float4*>(gb + t_ * 32 + mqs * 4);        \
        RB = *reinterpret_cast<const float4*>(gb + t_ * 32 + mqs * 4 + 16);   \
    } while (0)

    // pack to bf16 pairs and write chunk (swizzled) into buffer NB
    #define PACK_WRITE(NB, C2, RA, RB)                                        \
    do {                                                                      \
        uint32_t d0, d1, d2, d3;                                              \
        asm("v_cvt_pk_bf16_f32 %0, %1, %2" : "=v"(d0) : "v"(RA.x), "v"(RB.x));\
        asm("v_cvt_pk_bf16_f32 %0, %1, %2" : "=v"(d1) : "v"(RA.y), "v"(RB.y));\
        asm("v_cvt_pk_bf16_f32 %0, %1, %2" : "=v"(d2) : "v"(RA.z), "v"(RB.z));\
        asm("v_cvt_pk_bf16_f32 %0, %1, %2" : "=v"(d3) : "v"(RA.w), "v"(RB.w));\
        const int c_ = (C2) ^ (srow & 7);                                     \
        *reinterpret_cast<uint4*>(&tile[(NB)][(srow * 16 + c_) * 4]) =        \
            make_uint4(d0, d1, d2, d3);                                       \
    } while (0)

    // compute uh[T][0..3] for my (b, i-row, m-quarter) from buffer NB
    #define COMP(NB, T)                                                       \
    do {                                                                      \
        const float* up = u + ((size_t)b * IN_CAPS + (T) * TILE_R + ir) * 8;  \
        const float4 u0 = *reinterpret_cast<const float4*>(up);               \
        const float4 u1 = *reinterpret_cast<const float4*>(up + 4);           \
        const float uc[8] = {u0.x, u0.y, u0.z, u0.w, u1.x, u1.y, u1.z, u1.w}; \
        float a0 = 0.f, a1 = 0.f, a2 = 0.f, a3 = 0.f;                         \
        _Pragma("unroll")                                                     \
        for (int t = 0; t < 4; ++t) {                                         \
            const int c_ = ((t << 2) | mq) ^ ir3;                             \
            const uint4 d = *reinterpret_cast<const uint4*>(                  \
                &tile[(NB)][(ir * 16 + c_) * 4]);                             \
            const float ue = uc[2 * t], uo = uc[2 * t + 1];                   \
            a0 = fmaf(ue, __uint_as_float(d.x << 16), a0);                    \
            a0 = fmaf(uo, __uint_as_float(d.x & 0xffff0000u), a0);            \
            a1 = fmaf(ue, __uint_as_float(d.y << 16), a1);                    \
            a1 = fmaf(uo, __uint_as_float(d.y & 0xffff0000u), a1);            \
            a2 = fmaf(ue, __uint_as_float(d.z << 16), a2);                    \
            a2 = fmaf(uo, __uint_as_float(d.z & 0xffff0000u), a2);            \
            a3 = fmaf(ue, __uint_as_float(d.w << 16), a3);                    \
            a3 = fmaf(uo, __uint_as_float(d.w & 0xffff0000u), a3);            \
        }                                                                     \
        uh[(T)][0] = a0; uh[(T)][1] = a1;                                     \
        uh[(T)][2] = a2; uh[(T)][3] = a3;                                     \
    } while (0)

    // step T: issue chunk-1 gloads (latency hides under COMP), compute T,
    // commit chunk-1, then chunk-2 (TLP covers). One barrier per step:
    // buf[(T+1)&1]'s last readers were step T-1, fenced by its end barrier.
    #define STEP(T)                                                           \
    do {                                                                      \
        if ((T) + 1 < NTILE) {                                                \
            float4 sA, sB;                                                    \
            GLOADS((T) + 1, sc0, sA, sB);                                     \
            COMP((T) & 1, T);                                                 \
            PACK_WRITE(((T) + 1) & 1, sc0, sA, sB);                           \
            float4 sC, sD;                                                    \
            GLOADS((T) + 1, sc0 + 8, sC, sD);                                 \
            PACK_WRITE(((T) + 1) & 1, sc0 + 8, sC, sD);                       \
        } else {                                                              \
            COMP((T) & 1, T);                                                 \
        }                                                                     \
        __syncthreads();                                                      \
    } while (0)

    // ---- prologue: stage tile 0 ----
    {
        float4 sA, sB;
        GLOADS(0, sc0, sA, sB);
        PACK_WRITE(0, sc0, sA, sB);
        GLOADS(0, sc0 + 8, sA, sB);
        PACK_WRITE(0, sc0 + 8, sA, sB);
    }
    __syncthreads();

    STEP(0); STEP(1); STEP(2); STEP(3); STEP(4);
    STEP(5); STEP(6); STEP(7); STEP(8);
    #undef STEP
    #undef COMP
    #undef PACK_WRITE
    #undef GLOADS

    // ================= routing iterations =================
    // exp-domain logits: e[r] = exp(b[r]); iter 0 is exp(0) = 1 exactly.
    float e[NTILE];
    #pragma unroll
    for (int r = 0; r < NTILE; ++r) e[r] = 1.0f;
    float vv[4];
    const int grp = lane & 7;                // (mq<<1)|bl

    for (int it = 0; it < ITERS; ++it) {
        float esum = 0.0f;
        #pragma unroll
        for (int r = 0; r < NTILE; ++r) esum += e[r];
        esum += __shfl_xor(esum, 8);
        esum += __shfl_xor(esum, 16);
        esum += __shfl_xor(esum, 32);

        float sp0 = 0.f, sp1 = 0.f, sp2 = 0.f, sp3 = 0.f;
        #pragma unroll
        for (int r = 0; r < NTILE; ++r) {
            sp0 = fmaf(e[r], uh[r][0], sp0);
            sp1 = fmaf(e[r], uh[r][1], sp1);
            sp2 = fmaf(e[r], uh[r][2], sp2);
            sp3 = fmaf(e[r], uh[r][3], sp3);
        }
        sp0 += __shfl_xor(sp0, 8);  sp1 += __shfl_xor(sp1, 8);
        sp2 += __shfl_xor(sp2, 8);  sp3 += __shfl_xor(sp3, 8);
        sp0 += __shfl_xor(sp0, 16); sp1 += __shfl_xor(sp1, 16);
        sp2 += __shfl_xor(sp2, 16); sp3 += __shfl_xor(sp3, 16);
        sp0 += __shfl_xor(sp0, 32); sp1 += __shfl_xor(sp1, 32);
        sp2 += __shfl_xor(sp2, 32); sp3 += __shfl_xor(sp3, 32);

        if (lane < 8) {   // lane == grp of ir-group 0; [grp][q] layout
            red_es[lane * NW + wv] = esum;
            *reinterpret_cast<float4*>(&red_m[(lane * NW + wv) * 4]) =
                make_float4(sp0, sp1, sp2, sp3);
        }
        __syncthreads();
        float gsum = 0.0f;
        float sa0 = 0.f, sa1 = 0.f, sa2 = 0.f, sa3 = 0.f;
        #pragma unroll
        for (int q = 0; q < NW; ++q) {
            gsum += red_es[grp * NW + q];
            const float4 rm =
                *reinterpret_cast<const float4*>(&red_m[(grp * NW + q) * 4]);
            sa0 += rm.x; sa1 += rm.y; sa2 += rm.z; sa3 += rm.w;
        }
        __syncthreads();   // reads done before next iteration's writes

        const float cinv = 1.0f / gsum;
        vv[0] = sa0 * cinv; vv[1] = sa1 * cinv;
        vv[2] = sa2 * cinv; vv[3] = sa3 * cinv;
        float s2 = fmaf(vv[0], vv[0], fmaf(vv[1], vv[1],
                   fmaf(vv[2], vv[2], vv[3] * vv[3])));
        s2 += __shfl_xor(s2, 2);   // combine the 4 m-quarters (same bl)
        s2 += __shfl_xor(s2, 4);
        const float scale = (s2 / (1.0f + s2)) * rsqrtf(s2 + 1e-8f);
        vv[0] *= scale; vv[1] *= scale; vv[2] *= scale; vv[3] *= scale;

        // logit update: a = sum_m v[m]*uh[i][m]; combine mq via masks 2,4
        if (it < ITERS - 1) {
            #pragma unroll
            for (int r = 0; r < NTILE; ++r) {
                float a = fmaf(vv[0], uh[r][0], fmaf(vv[1], uh[r][1],
                          fmaf(vv[2], uh[r][2], vv[3] * uh[r][3])));
                a += __shfl_xor(a, 2);
                a += __shfl_xor(a, 4);
                e[r] *= __expf(a);
            }
        }
    }

    // ---- write v[b0+bl, j, mq*4 .. mq*4+3] ----
    if (tid < 8) {
        float4* op = reinterpret_cast<float4*>(
            out + ((size_t)(b0 + bl) * OUT_CAPS + j) * OUT_D + mq * 4);
        *op = make_float4(vv[0], vv[1], vv[2], vv[3]);
    }
}

extern "C" void kernel_launch(void* const* d_in, const int* in_sizes, int n_in,
                              void* d_out, int out_size, void* d_ws, size_t ws_size,
                              hipStream_t stream) {
    const float* u = (const float*)d_in[0];   // [128, 1152, 8]
    const float* w = (const float*)d_in[1];   // [1152, 32, 8, 16]
    float* out     = (float*)d_out;           // [128, 32, 16]
    (void)in_sizes; (void)n_in; (void)out_size; (void)d_ws; (void)ws_size;

    dim3 grid(OUT_CAPS * (B_SZ / G));   // 32 j x 64 batch-pairs = 2048 blocks
    dim3 block(THREADS);                // 1024 threads = 16 waves
    hipLaunchKernelGGL(caps_route, grid, block, 0, stream, u, w, out);
}

// Round 8
// 215.992 us; speedup vs baseline: 1.0403x; 1.0403x over previous
//
#include <hip/hip_runtime.h>
#include <stdint.h>

// Problem constants (fixed by setup_inputs)
constexpr int B_SZ     = 128;
constexpr int IN_CAPS  = 1152;
constexpr int OUT_CAPS = 32;
constexpr int OUT_D    = 16;

constexpr int THREADS  = 512;               // 8 waves
constexpr int GB       = 8;                 // b's per block
constexpr int TILE_R   = 64;                // i-rows per W tile
constexpr int NTILE    = IN_CAPS / TILE_R;  // 18

// async global->LDS, 16B per lane, dest = wave-uniform base + lane*16
typedef const uint32_t __attribute__((address_space(1)))* gptr_t;
typedef uint32_t       __attribute__((address_space(3)))* lptr_t;
__device__ __forceinline__ void async_copy16(const float* g, float* l) {
    __builtin_amdgcn_global_load_lds((gptr_t)g, (lptr_t)l, 16, 0, 0);
}

// u_hat is NEVER stored (R2-R7 all fought register spill on uh[NTILE][..]).
// Routing identity: logit_k[b,i] = (sum_{k'<k} v_k')·u_hat[b,i]  (linear!),
// so keep vsum[16] and recompute u_hat on the fly in 3 sweeps over W:
//   sweep0: e=1       : s~ += uh;           v0 = squash(s~/1152)
//   sweep1: e=exp(v0·uh): s~ += e·uh, den+=e; v1 = squash(s~/den)
//   sweep2: e=exp(vsum·uh): ...              v2 -> out
//
// Block = (j, 8 b's); thread = (b = tid&7, ipar = tid>>3) owns one W row per
// tile. W tile in LDS as [chunk c 0..31][row 0..63][4 f32]: a wave-read of
// chunk c touches 8 CONSECUTIVE 16B chunks (rows ipar..ipar+7) = 8 distinct
// bank groups, 8-lane broadcast each -> conflict-free BY LAYOUT (R5/R6/R7
// swizzle attempts all mispredicted banks). global_load_lds: issue q stages
// column c = wv*4+q -> dest base c*1KB wave-uniform + lane*16B, source row
// per-lane. Double buffer 2x32KB + red 5KB + vlds = 70KB -> 2 blocks/CU.
__global__ __launch_bounds__(THREADS, 2) void caps_route(
    const float* __restrict__ u,   // [B, IN_CAPS, 8]
    const float* __restrict__ w,   // [IN_CAPS, OUT_CAPS, 8, 16]
    float* __restrict__ out)       // [B, OUT_CAPS, OUT_D]
{
    __shared__ __align__(16) float tile[2][32 * 64 * 4];   // 2 x 32 KB
    __shared__ __align__(16) float red[8 * 8 * 20];        // [wave][b][16+den]
    __shared__ float vlds[GB * OUT_D];                     // running vsum

    // Bijective XCD swizzle (512 % 8 == 0): j-major ids -> each XCD's L2
    // holds 4 j-columns (9.4 MB f32... 4 x 589KB = 2.3MB hot per sweep).
    const int nwg = gridDim.x;               // 512
    const int bid = blockIdx.x;
    const int wid = (bid & 7) * (nwg >> 3) + (bid >> 3);
    const int j   = wid >> 4;                // 0..31
    const int b0  = (wid & 15) * GB;         // 0..120 step 8

    const int tid  = threadIdx.x;
    const int lane = tid & 63;
    const int wv   = tid >> 6;               // wave 0..7
    const int b    = tid & 7;                // my batch within group
    const int ipar = tid >> 3;               // my row in tile, 0..63

    const float* wj = w + (size_t)j * 128;   // + i*4096 + c*4
    const float* ub = u + (size_t)(b0 + b) * IN_CAPS * 8;

    float st[16];        // s~ accumulator
    float vs[16];        // vsum (past v's)
    float uh[16];        // u_hat, recomputed per (i, tile)
    float den;
    float4 ua0, ua1, ub0, ub1;

    // stage W tile T into LDS buffer NB: 4 issues/wave, column c per issue
    #define STAGE(NB, T)                                                      \
    do {                                                                      \
        _Pragma("unroll")                                                     \
        for (int q = 0; q < 4; ++q) {                                         \
            const int c = wv * 4 + q;                                         \
            const float* gsrc = wj + (size_t)((T) * TILE_R + lane) * 4096 + c * 4; \
            async_copy16(gsrc, &tile[(NB)][c * 256]);                         \
        }                                                                     \
    } while (0)

    #define ULOAD(T, U0, U1)                                                  \
    do {                                                                      \
        const float* up = ub + (size_t)((T) * TILE_R + ipar) * 8;             \
        U0 = *reinterpret_cast<const float4*>(up);                            \
        U1 = *reinterpret_cast<const float4*>(up + 4);                        \
    } while (0)

    // recompute uh[16] for (b, i = T*64+ipar) from buffer NB, then fold into
    // the sweep-K accumulators. K is a literal -> branches fold away.
    #define COMP(NB, K, U0, U1)                                               \
    do {                                                                      \
        const float uc[8] = {U0.x, U0.y, U0.z, U0.w, U1.x, U1.y, U1.z, U1.w}; \
        _Pragma("unroll")                                                     \
        for (int m = 0; m < 16; ++m) uh[m] = 0.0f;                            \
        _Pragma("unroll")                                                     \
        for (int c = 0; c < 32; ++c) {                                        \
            const float4 wc = *reinterpret_cast<const float4*>(               \
                &tile[(NB)][(c * 64 + ipar) * 4]);                            \
            const float uv = uc[c >> 2];                                      \
            const int   mb = (c & 3) * 4;                                     \
            uh[mb + 0] = fmaf(uv, wc.x, uh[mb + 0]);                          \
            uh[mb + 1] = fmaf(uv, wc.y, uh[mb + 1]);                          \
            uh[mb + 2] = fmaf(uv, wc.z, uh[mb + 2]);                          \
            uh[mb + 3] = fmaf(uv, wc.w, uh[mb + 3]);                          \
        }                                                                     \
        if ((K) == 0) {                                                       \
            _Pragma("unroll")                                                 \
            for (int m = 0; m < 16; ++m) st[m] += uh[m];                      \
        } else {                                                              \
            float l0 = vs[0] * uh[0], l1 = vs[1] * uh[1];                     \
            float l2 = vs[2] * uh[2], l3 = vs[3] * uh[3];                     \
            _Pragma("unroll")                                                 \
            for (int m = 4; m < 16; m += 4) {                                 \
                l0 = fmaf(vs[m + 0], uh[m + 0], l0);                          \
                l1 = fmaf(vs[m + 1], uh[m + 1], l1);                          \
                l2 = fmaf(vs[m + 2], uh[m + 2], l2);                          \
                l3 = fmaf(vs[m + 3], uh[m + 3], l3);                          \
            }                                                                 \
            const float e = __expf((l0 + l1) + (l2 + l3));                    \
            den += e;                                                         \
            _Pragma("unroll")                                                 \
            for (int m = 0; m < 16; ++m) st[m] = fmaf(e, uh[m], st[m]);       \
        }                                                                     \
    } while (0)

    // end-of-sweep: reduce {s~[16], den} over 64 ipar per b; squash; update
    // vlds (vsum) or write out.
    #define REDUCE(K)                                                         \
    do {                                                                      \
        _Pragma("unroll")                                                     \
        for (int m = 0; m < 16; ++m) {                                        \
            st[m] += __shfl_xor(st[m], 8);                                    \
            st[m] += __shfl_xor(st[m], 16);                                   \
            st[m] += __shfl_xor(st[m], 32);                                   \
        }                                                                     \
        if ((K) > 0) {                                                        \
            den += __shfl_xor(den, 8);                                        \
            den += __shfl_xor(den, 16);                                       \
            den += __shfl_xor(den, 32);                                       \
        }                                                                     \
        if (lane < 8) {  /* lane == b, ipar-subgroup 0 */                     \
            float* rb = &red[(wv * 8 + lane) * 20];                           \
            *reinterpret_cast<float4*>(rb +  0) = make_float4(st[0],  st[1],  st[2],  st[3]);  \
            *reinterpret_cast<float4*>(rb +  4) = make_float4(st[4],  st[5],  st[6],  st[7]);  \
            *reinterpret_cast<float4*>(rb +  8) = make_float4(st[8],  st[9],  st[10], st[11]); \
            *reinterpret_cast<float4*>(rb + 12) = make_float4(st[12], st[13], st[14], st[15]); \
            rb[16] = den;                                                     \
        }                                                                     \
        __syncthreads();                                                      \
        if (tid < 128) {                                                      \
            const int br = tid >> 4, m = tid & 15;                            \
            float acc = 0.0f, dsum = 0.0f;                                    \
            _Pragma("unroll")                                                 \
            for (int q = 0; q < 8; ++q) {                                     \
                acc  += red[(q * 8 + br) * 20 + m];                           \
                dsum += red[(q * 8 + br) * 20 + 16];                          \
            }                                                                 \
            const float dn = ((K) == 0) ? (float)IN_CAPS : dsum;              \
            const float sm = acc / dn;                                        \
            float s2 = sm * sm;                                               \
            s2 += __shfl_xor(s2, 1); s2 += __shfl_xor(s2, 2);                 \
            s2 += __shfl_xor(s2, 4); s2 += __shfl_xor(s2, 8);                 \
            const float v = sm * (s2 / (1.0f + s2)) * rsqrtf(s2 + 1e-8f);     \
            if ((K) == 0)      vlds[br * 16 + m] = v;                         \
            else if ((K) == 1) vlds[br * 16 + m] += v;                        \
            else out[((size_t)(b0 + br) * OUT_CAPS + j) * OUT_D + m] = v;     \
        }                                                                     \
        __syncthreads();                                                      \
    } while (0)

    // one sweep over all 1152 i: double-buffered tile pairs, runtime tile
    // index (keeps code size sane), literal buffer parity & K.
    #define SWEEP(K)                                                          \
    do {                                                                      \
        if ((K) > 0) {                                                        \
            _Pragma("unroll")                                                 \
            for (int m = 0; m < 16; ++m) vs[m] = vlds[b * 16 + m];            \
        }                                                                     \
        _Pragma("unroll")                                                     \
        for (int m = 0; m < 16; ++m) st[m] = 0.0f;                            \
        den = 0.0f;                                                           \
        STAGE(0, 0); ULOAD(0, ua0, ua1);                                      \
        __syncthreads();                                                      \
        _Pragma("unroll 1")                                                   \
        for (int t2 = 0; t2 < NTILE / 2; ++t2) {                              \
            const int Tb = 2 * t2 + 1;                                        \
            STAGE(1, Tb); ULOAD(Tb, ub0, ub1);                                \
            COMP(0, K, ua0, ua1);                                             \
            __syncthreads();                                                  \
            if (Tb < NTILE - 1) { STAGE(0, Tb + 1); ULOAD(Tb + 1, ua0, ua1); }\
            COMP(1, K, ub0, ub1);                                             \
            __syncthreads();                                                  \
        }                                                                     \
        REDUCE(K);                                                            \
    } while (0)

    SWEEP(0);
    SWEEP(1);
    SWEEP(2);

    #undef SWEEP
    #undef REDUCE
    #undef COMP
    #undef ULOAD
    #undef STAGE
}

extern "C" void kernel_launch(void* const* d_in, const int* in_sizes, int n_in,
                              void* d_out, int out_size, void* d_ws, size_t ws_size,
                              hipStream_t stream) {
    const float* u = (const float*)d_in[0];   // [128, 1152, 8]
    const float* w = (const float*)d_in[1];   // [1152, 32, 8, 16]
    float* out     = (float*)d_out;           // [128, 32, 16]
    (void)in_sizes; (void)n_in; (void)out_size; (void)d_ws; (void)ws_size;

    dim3 grid(OUT_CAPS * (B_SZ / GB));   // 32 j x 16 b-groups = 512 blocks
    dim3 block(THREADS);                 // 512 threads = 8 waves
    hipLaunchKernelGGL(caps_route, grid, block, 0, stream, u, w, out);
}